// Round 1
// baseline (1144.515 us; speedup 1.0000x reference)
//
#include <hip/hip_runtime.h>

// BasicGNN fused kernel for MI355X (gfx950).
// Design: block = 32 batch rows x all 24 nodes; 4 waves, wave t = output col-tile t.
// Per layer: per-node [32x64]x[64x64] GEMM via mfma_f32_16x16x32_bf16 with 2-term
// precision split (act->bf16 RTNE, W = Whi + Wlo), fp32 accum; adjacency aggregation
// done in-register in the D-fragment domain; activations ping in-place in LDS (bf16).
// Weights pre-swizzled to frag-contiguous bf16 hi/lo layout in d_ws by prep kernel.

typedef unsigned short ushort_t;
typedef unsigned int uint32;
typedef float f32x4 __attribute__((ext_vector_type(4)));
typedef __bf16 bf16x8 __attribute__((ext_vector_type(8)));
typedef ushort_t us8 __attribute__((ext_vector_type(8)));

#define XS_STRIDE 72               // bf16 elems per row; 144B rows: 16B-aligned, good banks
#define WP_LAYER (24 * 16 * 512)   // ushorts per layer of prepped weights (384 frags * 512)

// SMPL skeleton adjacency (compile-time): undirected edges (i, parent[i]), i=1..23
__device__ constexpr int NBR_START[25] = {0,3,5,7,9,11,13,15,17,19,23,24,25,27,29,31,32,34,36,38,40,42,44,45,46};
__device__ constexpr int NBR_M[46] = {
  1,2,3,  0,4,  0,5,  0,6,  1,7,  2,8,  3,9,  4,10, 5,11, 6,12,13,14,
  7,  8,  9,15, 9,16, 9,17, 12,  13,18, 14,19, 16,20, 17,21, 18,22, 19,23, 20, 21 };

__device__ __forceinline__ ushort_t f2bf(float f) {   // RTNE f32 -> bf16 bits
  uint32 u = __float_as_uint(f);
  u += 0x7FFFu + ((u >> 16) & 1u);
  return (ushort_t)(u >> 16);
}
__device__ __forceinline__ float bf2f(ushort_t h) {
  return __uint_as_float(((uint32)h) << 16);
}

__device__ __forceinline__ f32x4 mfma16(us8 a, us8 b, f32x4 c) {
  return __builtin_amdgcn_mfma_f32_16x16x32_bf16(
      __builtin_bit_cast(bf16x8, a), __builtin_bit_cast(bf16x8, b), c, 0, 0, 0);
}

// ---- Weight prep: fp32 [24][in][out] -> frag layout [layer][k][t][s][p][lane][8] bf16
// frag f: p=f&1 (0=hi,1=lo), s=(f>>1)&1 (K-step), t=(f>>2)&3 (col tile), k,layer from f>>4.
// Lane l of B-frag holds W[lin = 32s + (l>>4)*8 + j][c = 16t + (l&15)], j=0..7 contiguous.
__global__ void prep_weights(const float* __restrict__ w0, const float* __restrict__ w1,
                             const float* __restrict__ w2, const float* __restrict__ w3,
                             ushort_t* __restrict__ WP) {
  int tid = blockIdx.x * 256 + threadIdx.x;   // exactly 1536 frags * 64 lanes = 98304
  int l = tid & 63;
  int f = tid >> 6;
  int p = f & 1, s = (f >> 1) & 1, t = (f >> 2) & 3;
  int kl = f >> 4;
  int k = kl % 24, layer = kl / 24;
  const float* w = (layer == 0) ? w0 : (layer == 1) ? w1 : (layer == 2) ? w2 : w3;
  int stride = (layer == 3) ? 65 : 64;
  int c = t * 16 + (l & 15);
  int lin0 = s * 32 + ((l >> 4) << 3);
  const float* src = w + k * 64 * stride + c;
  us8 outv;
#pragma unroll
  for (int j = 0; j < 8; ++j) {
    float v = src[(lin0 + j) * stride];
    ushort_t hi = f2bf(v);
    outv[j] = (p == 0) ? hi : f2bf(v - bf2f(hi));
  }
  *(us8*)(WP + (size_t)f * 512 + l * 8) = outv;
}

__global__ __launch_bounds__(256, 1) void gnn_fused(
    const float* __restrict__ x, const ushort_t* __restrict__ WP,
    const float* __restrict__ w3,
    const float* __restrict__ aw0, const float* __restrict__ aw1,
    const float* __restrict__ aw2, const float* __restrict__ aw3,
    const float* __restrict__ b0, const float* __restrict__ b1,
    const float* __restrict__ b2, const float* __restrict__ b3,
    float* __restrict__ out) {
  __shared__ __align__(16) ushort_t Xs[24 * 32 * XS_STRIDE]; // activations, bf16
  __shared__ float H64[24 * 32];   // layer-3 col-64 pre-aggregation
  __shared__ float W3c[24 * 64];   // W3[:, :, 64] staged

  const int tid = threadIdx.x;
  const int l = tid & 63;
  const int wv = tid >> 6;         // wave id = col tile t (0..3)
  const int lr = l & 15, lg = l >> 4;
  const int b0r = blockIdx.x * 32; // 2048 blocks * 32 rows = 65536

  // ---- stage x -> Xs (bf16 RTNE, root node masked to 0)
  {
    const float4* xv = (const float4*)(x + (size_t)b0r * 1536);
    for (int i = tid; i < 12288; i += 256) {
      float4 v = xv[i];
      int flat = i << 2;
      int r = flat / 1536;
      int rem = flat - r * 1536;
      int k = rem >> 6, c = rem & 63;
      uint32 u01 = (uint32)f2bf(v.x) | ((uint32)f2bf(v.y) << 16);
      uint32 u23 = (uint32)f2bf(v.z) | ((uint32)f2bf(v.w) << 16);
      if (k == 0) { u01 = 0u; u23 = 0u; }   // mask_root
      uint2 uu; uu.x = u01; uu.y = u23;
      *(uint2*)&Xs[(k * 32 + r) * XS_STRIDE + c] = uu;
    }
    for (int i = tid; i < 1536; i += 256) {  // W3 column 64
      int k = i >> 6, lin = i & 63;
      W3c[i] = w3[k * 4160 + lin * 65 + 64];
    }
  }
  __syncthreads();

  f32x4 acc[24][2];   // [node][row-tile], D-frags: row = rt*16 + 4*lg + j, col = 16*wv + lr
  const int cw = (wv << 4) | lr;

  // ---- MFMA phase: all 24 node-GEMMs for this wave's col tile, both row tiles.
  // acc[k] = n[k] @ (Whi[k] + Wlo[k]), fp32 accum. A 2-deep / B 3-deep prefetch.
  auto mfma_phase = [&](const ushort_t* __restrict__ wpL) {
    us8 A[2][2][2];   // [buf][rt][s]
    us8 Bb[3][4];     // [buf][s*2+p]
    auto load_A = [&](int k, us8 a[2][2]) {
#pragma unroll
      for (int rt = 0; rt < 2; ++rt)
#pragma unroll
        for (int s = 0; s < 2; ++s)
          a[rt][s] = *(const us8*)&Xs[(k * 32 + rt * 16 + lr) * XS_STRIDE + s * 32 + lg * 8];
    };
    auto load_B = [&](int k, us8 b[4]) {
      const ushort_t* bp = wpL + (size_t)(k * 16 + wv * 4) * 512 + l * 8;
#pragma unroll
      for (int q = 0; q < 4; ++q) b[q] = *(const us8*)(bp + q * 512);
    };
    load_A(0, A[0]);
    load_B(0, Bb[0]);
    load_B(1, Bb[1]);
#pragma unroll
    for (int k = 0; k < 24; ++k) {
      if (k < 22) load_B(k + 2, Bb[(k + 2) % 3]);
      if (k < 23) load_A(k + 1, A[(k + 1) & 1]);
      const us8(*a)[2] = A[k & 1];
      const us8* b = Bb[k % 3];
      const f32x4 z = {0.f, 0.f, 0.f, 0.f};
      f32x4 o0, o1;
      o0 = mfma16(a[0][0], b[0], z);   // s0 * Whi
      o1 = mfma16(a[1][0], b[0], z);
      o0 = mfma16(a[0][1], b[2], o0);  // s1 * Whi
      o1 = mfma16(a[1][1], b[2], o1);
      o0 = mfma16(a[0][0], b[1], o0);  // s0 * Wlo
      o1 = mfma16(a[1][0], b[1], o1);
      o0 = mfma16(a[0][1], b[3], o0);  // s1 * Wlo
      o1 = mfma16(a[1][1], b[3], o1);
      acc[k][0] = o0;
      acc[k][1] = o1;
    }
  };

  // ---- layers 0..2: mfma -> in-register aggregation -> bias -> relu -> bf16 in-place
#pragma unroll 1
  for (int L = 0; L < 3; ++L) {
    mfma_phase(WP + (size_t)L * WP_LAYER);
    __syncthreads();   // all Xs reads done before in-place overwrite
    const float* awL = (L == 0) ? aw0 : (L == 1) ? aw1 : aw2;
    const float* bL  = (L == 0) ? b0  : (L == 1) ? b1  : b2;
    const float bv = bL[cw];
#pragma unroll
    for (int k = 0; k < 24; ++k) {
#pragma unroll
      for (int rt = 0; rt < 2; ++rt) {
        f32x4 h = acc[k][rt];
#pragma unroll
        for (int e = NBR_START[k]; e < NBR_START[k + 1]; ++e) {
          const int m = NBR_M[e];
          const float av = awL[k * 24 + m];  // uniform -> s_load; diag coeff is exactly 1
          const f32x4 nb = acc[m][rt];
#pragma unroll
          for (int j = 0; j < 4; ++j) h[j] += av * nb[j];
        }
        ushort_t* dst = &Xs[(k * 32 + rt * 16 + (lg << 2)) * XS_STRIDE + cw];
#pragma unroll
        for (int j = 0; j < 4; ++j)
          dst[j * XS_STRIDE] = f2bf(fmaxf(h[j] + bv, 0.0f));
      }
    }
    __syncthreads();   // writes visible before next layer's reads
  }

  // ---- layer 3: cols 0..63 via MFMA; col 64 via VALU dot; no relu; store to global
  mfma_phase(WP + (size_t)3 * WP_LAYER);
  // col-64 pre-aggregation dots (reads Xs, no Xs writes in layer 3 -> no hazard)
#pragma unroll
  for (int it = 0; it < 3; ++it) {           // 768 (k,r) tasks = 3 * 256 threads
    int task = tid + it * 256;
    int kk = task >> 5, rr = task & 31;
    float s = 0.f;
#pragma unroll
    for (int c8 = 0; c8 < 8; ++c8) {
      us8 nn = *(const us8*)&Xs[(kk * 32 + rr) * XS_STRIDE + c8 * 8];
#pragma unroll
      for (int j = 0; j < 8; ++j) s += bf2f(nn[j]) * W3c[kk * 64 + c8 * 8 + j];
    }
    H64[(kk << 5) | rr] = s;
  }
  __syncthreads();

  {
    const float bv = b3[cw];
#pragma unroll
    for (int k = 0; k < 24; ++k) {
#pragma unroll
      for (int rt = 0; rt < 2; ++rt) {
        f32x4 h = acc[k][rt];
#pragma unroll
        for (int e = NBR_START[k]; e < NBR_START[k + 1]; ++e) {
          const int m = NBR_M[e];
          const float av = aw3[k * 24 + m];
          const f32x4 nb = acc[m][rt];
#pragma unroll
        for (int j = 0; j < 4; ++j) h[j] += av * nb[j];
        }
#pragma unroll
        for (int j = 0; j < 4; ++j) {
          int bb = b0r + rt * 16 + (lg << 2) + j;
          out[((size_t)bb * 24 + k) * 65 + cw] = h[j] + bv;
        }
      }
    }
    // col 64: aggregate H64 + bias, store
    const float b64v = b3[64];
#pragma unroll
    for (int it = 0; it < 3; ++it) {
      int task = tid + it * 256;
      int kk = task >> 5, rr = task & 31;
      float v = H64[(kk << 5) | rr];
      for (int e = NBR_START[kk]; e < NBR_START[kk + 1]; ++e) {
        const int m = NBR_M[e];
        v += aw3[kk * 24 + m] * H64[(m << 5) | rr];
      }
      out[((size_t)(b0r + rr) * 24 + kk) * 65 + 64] = v + b64v;
    }
  }
}

extern "C" void kernel_launch(void* const* d_in, const int* in_sizes, int n_in,
                              void* d_out, int out_size, void* d_ws, size_t ws_size,
                              hipStream_t stream) {
  const float* x   = (const float*)d_in[0];
  const float* w0  = (const float*)d_in[1];
  const float* w1  = (const float*)d_in[2];
  const float* w2  = (const float*)d_in[3];
  const float* w3  = (const float*)d_in[4];
  const float* aw0 = (const float*)d_in[5];
  const float* aw1 = (const float*)d_in[6];
  const float* aw2 = (const float*)d_in[7];
  const float* aw3 = (const float*)d_in[8];
  const float* b0  = (const float*)d_in[9];
  const float* b1  = (const float*)d_in[10];
  const float* b2  = (const float*)d_in[11];
  const float* b3  = (const float*)d_in[12];
  ushort_t* WP = (ushort_t*)d_ws;   // needs 1,572,864 bytes

  prep_weights<<<384, 256, 0, stream>>>(w0, w1, w2, w3, WP);
  gnn_fused<<<2048, 256, 0, stream>>>(x, WP, w3, aw0, aw1, aw2, aw3,
                                      b0, b1, b2, b3, (float*)d_out);
}